// Round 9
// baseline (422.147 us; speedup 1.0000x reference)
//
#include <hip/hip_runtime.h>

typedef __bf16 bf16_t;
typedef __bf16 bf16x8 __attribute__((ext_vector_type(8)));
typedef __bf16 bf16x4 __attribute__((ext_vector_type(4)));
typedef float  f32x4  __attribute__((ext_vector_type(4)));

#define S_LEN 2048
#define NH    16
#define DH    64
#define DM    1024
#define BATCH 4
#define LOG2E 1.44269504088896f
#define NEGB  (-1.44269504e10f)

static __device__ __forceinline__ f32x4 mfma16(bf16x8 a, bf16x8 b, f32x4 c) {
    return __builtin_amdgcn_mfma_f32_16x16x32_bf16(a, b, c, 0, 0, 0);
}

// bare v_exp_f32 (2^x): OCML exp2f adds range-handling VALU ops we don't need
// (|scores| are small); __expf would re-add the log2e multiply we folded away.
#if __has_builtin(__builtin_amdgcn_exp2f)
static __device__ __forceinline__ float exp2_hw(float x) {
    return __builtin_amdgcn_exp2f(x);
}
#else
static __device__ __forceinline__ float exp2_hw(float x) {
    float r;
    asm("v_exp_f32 %0, %1" : "=v"(r) : "v"(x));
    return r;
}
#endif

// async global->LDS, 16B per lane. lds base is wave-uniform; HW adds lane*16.
static __device__ __forceinline__ void gl_lds16(const bf16_t* g, bf16_t* l) {
    __builtin_amdgcn_global_load_lds(
        (const __attribute__((address_space(1))) unsigned int*)g,
        (__attribute__((address_space(3))) unsigned int*)l, 16, 0, 0);
}

// ---------------- fp32 -> bf16 convert, 3 tensors in one dispatch ------------
__global__ __launch_bounds__(256) void cvt3_bf16(const float* __restrict__ s0,
                                                 const float* __restrict__ s1,
                                                 const float* __restrict__ s2,
                                                 bf16_t* __restrict__ d0,
                                                 bf16_t* __restrict__ d1,
                                                 bf16_t* __restrict__ d2, int n) {
    int z = blockIdx.y;
    const float* s = (z == 0) ? s0 : (z == 1) ? s1 : s2;
    bf16_t*      d = (z == 0) ? d0 : (z == 1) ? d1 : d2;
    int i = (blockIdx.x * 256 + threadIdx.x) * 8;
    if (i >= n) return;
    const float4* q = (const float4*)(s + i);
    float4 a = q[0], b = q[1];
    bf16x8 r;
    r[0] = (bf16_t)a.x; r[1] = (bf16_t)a.y; r[2] = (bf16_t)a.z; r[3] = (bf16_t)a.w;
    r[4] = (bf16_t)b.x; r[5] = (bf16_t)b.y; r[6] = (bf16_t)b.z; r[7] = (bf16_t)b.w;
    *(bf16x8*)(d + i) = r;
}

// ---------------- weight transpose+convert: Wt[n][k] = scale * W[k][n] -------
__global__ __launch_bounds__(256) void wtrans(const float* __restrict__ W,
                                              bf16_t* __restrict__ Wt, float scale) {
    __shared__ bf16_t tile[32][33];
    int x = threadIdx.x, ty = threadIdx.y;
    int bx = blockIdx.x * 32, by = blockIdx.y * 32;
#pragma unroll
    for (int i = 0; i < 4; ++i) {
        int y = ty * 4 + i;
        tile[y][x] = (bf16_t)(W[(by + y) * DM + bx + x] * scale);
    }
    __syncthreads();
#pragma unroll
    for (int i = 0; i < 4; ++i) {
        int y = ty * 4 + i;
        Wt[(bx + y) * DM + by + x] = tile[x][y];
    }
}

// ---------------- bf16 transpose: dst[C][R] = src[R][C] ----------------------
__global__ __launch_bounds__(256) void btrans(const bf16_t* __restrict__ src,
                                              bf16_t* __restrict__ dst,
                                              int R, int C) {
    __shared__ bf16_t tile[32][33];
    int x = threadIdx.x, ty = threadIdx.y;
    int bx = blockIdx.x * 32, by = blockIdx.y * 32;   // bx: col, by: row
#pragma unroll
    for (int i = 0; i < 4; ++i) {
        int y = ty * 4 + i;
        tile[y][x] = src[(size_t)(by + y) * C + bx + x];
    }
    __syncthreads();
#pragma unroll
    for (int i = 0; i < 4; ++i) {
        int y = ty * 4 + i;
        dst[(size_t)(bx + y) * R + by + x] = tile[x][y];
    }
}

// ---------------- NT GEMM, 256x128 tile, BK=64, z-batched --------------------
template <typename CT>
__global__ __launch_bounds__(512) void gemm_nt_256(const bf16_t* __restrict__ A,
                                                   const bf16_t* __restrict__ Bt,
                                                   CT* __restrict__ C,
                                                   int M, int N, int K, float alpha,
                                                   size_t zsA, size_t zsB, size_t zsC) {
    __shared__ __align__(16) bf16_t As[2 * 256 * 32];  // [kk][row][32]
    __shared__ __align__(16) bf16_t Bs[2 * 128 * 32];
    A  += (size_t)blockIdx.z * zsA;
    Bt += (size_t)blockIdx.z * zsB;
    C  += (size_t)blockIdx.z * zsC;
    int tid = threadIdx.x, wave = tid >> 6, lane = tid & 63;
    int l15 = lane & 15, quad = lane >> 4;
    int wm = wave >> 1, wn = wave & 1;                 // 4 x 2 wave grid
    int bm = blockIdx.x * 256, bn = blockIdx.y * 128;
    int srow = lane >> 2, skx = (lane & 3) << 3;       // 16 rows x 4 chunks

    f32x4 acc[4][4] = {};

    for (int k0 = 0; k0 < K; k0 += 64) {
#pragma unroll
        for (int c = 0; c < 4; ++c) {
            int t = wave * 4 + c;
            int kk = t & 1, rb = (t >> 1) * 16;
            gl_lds16(A + (size_t)(bm + rb + srow) * K + k0 + kk * 32 + skx,
                     As + kk * 8192 + rb * 32);
        }
#pragma unroll
        for (int c = 0; c < 2; ++c) {
            int t = wave * 2 + c;
            int kk = t & 1, rb = (t >> 1) * 16;
            gl_lds16(Bt + (size_t)(bn + rb + srow) * K + k0 + kk * 32 + skx,
                     Bs + kk * 4096 + rb * 32);
        }
        __syncthreads();   // compiler drains vmcnt before s_barrier

#pragma unroll
        for (int kk = 0; kk < 2; ++kk) {
            bf16x8 af[4], bfr[4];
#pragma unroll
            for (int i = 0; i < 4; ++i)
                af[i] = *(const bf16x8*)(As + kk * 8192 +
                                         (wm * 64 + i * 16 + l15) * 32 + quad * 8);
#pragma unroll
            for (int j = 0; j < 4; ++j)
                bfr[j] = *(const bf16x8*)(Bs + kk * 4096 +
                                          (wn * 64 + j * 16 + l15) * 32 + quad * 8);
#pragma unroll
            for (int i = 0; i < 4; ++i)
#pragma unroll
                for (int j = 0; j < 4; ++j)
                    acc[i][j] = mfma16(af[i], bfr[j], acc[i][j]);
        }
        __syncthreads();
    }

#pragma unroll
    for (int i = 0; i < 4; ++i)
#pragma unroll
        for (int r = 0; r < 4; ++r) {
            int row = bm + wm * 64 + i * 16 + quad * 4 + r;
#pragma unroll
            for (int j = 0; j < 4; ++j)
                C[(size_t)row * N + bn + wn * 64 + j * 16 + l15] =
                    (CT)(acc[i][j][r] * alpha);
        }
}

// ---------------- per-batch V column mean (for fully-masked-row fallback) ----
__global__ __launch_bounds__(256) void vmean_kernel(const bf16_t* __restrict__ Vp,
                                                    float* __restrict__ Vm) {
    __shared__ float red[4][64];
    int z = blockIdx.y;
    int c = blockIdx.x * 64 + (threadIdx.x & 63);
    int rg = threadIdx.x >> 6;
    const bf16_t* p = Vp + (size_t)z * S_LEN * DM + (size_t)rg * (S_LEN / 4) * DM + c;
    float s = 0.f;
    for (int r = 0; r < S_LEN / 4; ++r) s += (float)p[(size_t)r * DM];
    red[rg][threadIdx.x & 63] = s;
    __syncthreads();
    if (threadIdx.x < 64) {
        float t = red[0][threadIdx.x] + red[1][threadIdx.x] +
                  red[2][threadIdx.x] + red[3][threadIdx.x];
        Vm[z * DM + blockIdx.x * 64 + threadIdx.x] = t * (1.0f / S_LEN);
    }
}

// ---------------- fused attention: barrier-free, global-fragment loads -------
// Swapped-operand S^T = mfma(K,Q) / ctx^T = mfma(V^T,P^T), no-max exp2-domain
// softmax (scores structurally bounded, masked -> exactly 0, dead rows via
// l == 0), 32 q-rows per wave (u = 0,1), 128 q-rows per block.
// Round-7 post-mortem: all pipes <26% busy -> latency-bound on the
// staging/barrier lockstep. So K/V LDS staging is REMOVED. K+V are only 32 MB
// total (L3-resident; 512 KB per (z,h) slice), and the MFMA A-fragment layout
// (lane&15 -> key/dh row, quad -> 16B chunk) maps directly to 64B-segment
// global loads, so fragments are loaded straight from Kp/VT through L2/L3.
// Only padb (read-only) and per-wave Ps remain in LDS -> NO barriers in the
// main loop; waves run fully independent with their own exact causal bound
// (dead tiles skipped, not barriered). u0/u1 reuse the same Ps rows
// sequentially (same-wave DS ops execute in order on the single LDS pipe).
// ctx may alias Qp: block reads only its own (rows x head) slice at start and
// writes only that same slice at the end; slices are disjoint across blocks.
__global__ __launch_bounds__(256, 3) void attn_kernel(const bf16_t* __restrict__ Qp,
                                                      const bf16_t* __restrict__ Kp,
                                                      const bf16_t* __restrict__ VT,
                                                      const int* __restrict__ Kini,
                                                      const float* __restrict__ Vmean,
                                                      bf16_t* __restrict__ ctx,
                                                      int ldv, int nqt) {
    __shared__ __align__(16) bf16_t Ps[4][16 * 72];  // per-wave P, u0/u1 reuse
    __shared__ bf16_t padb[2048];                    // pad bias 0 / -1.44e10

    int bid = blockIdx.x;
    int qt = nqt - 1 - (bid >> 6);                   // heavy tiles first
    int hz = bid & 63;
    int h = hz & 15, z = hz >> 4;
    int tid = threadIdx.x, wave = tid >> 6, lane = tid & 63;
    int l15 = lane & 15, quad = lane >> 4;
    int qb0 = qt * 128 + wave * 32;                  // u0: +0..15, u1: +16..31
    size_t rowz = (size_t)z * S_LEN;
    int nkeys = (qt + 1) * 128;                      // block's causal key span

    // pad-bias table, once per block
    for (int i = tid; i < nkeys; i += 256)
        padb[i] = (Kini[rowz + i] == 0) ? (bf16_t)NEGB : (bf16_t)(0.0f);
    __syncthreads();                                 // only barrier in kernel

    const bf16_t* qptr = Qp + (rowz + qb0 + l15) * DM + h * DH + quad * 8;
    bf16x8 qa00 = *(const bf16x8*)qptr;
    bf16x8 qa01 = *(const bf16x8*)(qptr + 32);
    bf16x8 qa10 = *(const bf16x8*)(qptr + 16 * DM);
    bf16x8 qa11 = *(const bf16x8*)(qptr + 16 * DM + 32);

    f32x4 o0[4] = {}, o1[4] = {};                    // ctx^T frags: col=q(l15)
    f32x4 l40 = {0.f,0.f,0.f,0.f}, l41 = {0.f,0.f,0.f,0.f};
    int q0 = qb0 + l15, q1 = q0 + 16;
    int q0max = qb0 + 15, q1max = qb0 + 31;

    const bf16_t* kbase = Kp + (rowz)*DM + h * DH;        // + key*DM
    const bf16_t* vbase = VT + (size_t)(h * DH) * ldv + rowz;  // + dh*ldv + key

    int wnt = (q1max >> 6) + 1;                      // this wave's exact bound
    for (int kt = 0; kt < wnt; ++kt) {
        int kb = kt * 64;
        bool live0 = (kb <= q0max);
        bool bnd = (kb + 63 > qb0);                  // boundary: apply causal
        f32x4 s1[4];
        // pass 1: K-fragments direct from global (L2/L3); u0 consumed per-ks
        // (exp+P-store), u1 kept raw in s1
#pragma unroll
        for (int ks = 0; ks < 4; ++ks) {
            const bf16_t* kp = kbase + (size_t)(kb + ks * 16 + l15) * DM + quad * 8;
            bf16x8 kf0 = *(const bf16x8*)kp;
            bf16x8 kf1 = *(const bf16x8*)(kp + 32);
            bf16x4 pb = *(const bf16x4*)(padb + kb + ks * 16 + quad * 4);
            f32x4 t1 = {0.f, 0.f, 0.f, 0.f};
            t1 = mfma16(kf0, qa10, t1);
            t1 = mfma16(kf1, qa11, t1);
#pragma unroll
            for (int r = 0; r < 4; ++r) t1[r] += (float)pb[r];
            if (bnd) {
#pragma unroll
                for (int r = 0; r < 4; ++r)
                    if (kb + ks * 16 + quad * 4 + r > q1) t1[r] = NEGB;
            }
            s1[ks] = t1;
            if (live0) {
                f32x4 t0 = {0.f, 0.f, 0.f, 0.f};
                t0 = mfma16(kf0, qa00, t0);
                t0 = mfma16(kf1, qa01, t0);
#pragma unroll
                for (int r = 0; r < 4; ++r) t0[r] += (float)pb[r];
                if (bnd) {
#pragma unroll
                    for (int r = 0; r < 4; ++r)
                        if (kb + ks * 16 + quad * 4 + r > q0) t0[r] = NEGB;
                }
#pragma unroll
                for (int r = 0; r < 4; ++r) t0[r] = exp2_hw(t0[r]);
                l40 += t0;
                bf16x4 pk;
#pragma unroll
                for (int r = 0; r < 4; ++r) pk[r] = (bf16_t)t0[r];
                *(bf16x4*)(Ps[wave] + l15 * 72 + ks * 16 + quad * 4) = pk;
            }
        }
        bf16x8 pa00, pa01;
        if (live0) {                                 // u0 P as B-frag
            pa00 = *(const bf16x8*)(Ps[wave] + l15 * 72 + quad * 8);
            pa01 = *(const bf16x8*)(Ps[wave] + l15 * 72 + 32 + quad * 8);
        }
        // pass 2: u1 exp + P-store (same Ps rows — after u0's reads)
#pragma unroll
        for (int ks = 0; ks < 4; ++ks) {
            f32x4 t1 = s1[ks];
#pragma unroll
            for (int r = 0; r < 4; ++r) t1[r] = exp2_hw(t1[r]);
            l41 += t1;
            bf16x4 pk;
#pragma unroll
            for (int r = 0; r < 4; ++r) pk[r] = (bf16_t)t1[r];
            *(bf16x4*)(Ps[wave] + l15 * 72 + ks * 16 + quad * 4) = pk;
        }
        bf16x8 pa10 = *(const bf16x8*)(Ps[wave] + l15 * 72 + quad * 8);
        bf16x8 pa11 = *(const bf16x8*)(Ps[wave] + l15 * 72 + 32 + quad * 8);
        // PV: V-fragments direct from global; shared reads feed both subtiles
#pragma unroll
        for (int j = 0; j < 4; ++j) {
            const bf16_t* vp = vbase + (size_t)(j * 16 + l15) * ldv + kb + quad * 8;
            bf16x8 vb0 = *(const bf16x8*)vp;
            bf16x8 vb1 = *(const bf16x8*)(vp + 32);
            o1[j] = mfma16(vb0, pa10, o1[j]);
            o1[j] = mfma16(vb1, pa11, o1[j]);
            if (live0) {
                o0[j] = mfma16(vb0, pa00, o0[j]);
                o0[j] = mfma16(vb1, pa01, o0[j]);
            }
        }
    }

    // epilogue per subtile: reduce l, scale, transpose through Ps (reused
    // sequentially; same-wave DS ordering), 16B coalesced global stores.
    const float* vm = Vmean + z * DM + h * DH;
    int rr = lane >> 2, cc = (lane & 3) * 16;
#pragma unroll
    for (int u = 0; u < 2; ++u) {
        f32x4 l4 = u ? l41 : l40;
        float l_ = (l4[0] + l4[1]) + (l4[2] + l4[3]);
        l_ += __shfl_xor(l_, 16);
        l_ += __shfl_xor(l_, 32);
        float inv = 1.0f / l_;
        bool dead = (l_ == 0.0f);
#pragma unroll
        for (int j = 0; j < 4; ++j) {
            f32x4 oj = u ? o1[j] : o0[j];
            bf16x4 c;
#pragma unroll
            for (int r = 0; r < 4; ++r) {
                float val = dead ? vm[j * 16 + quad * 4 + r] : oj[r] * inv;
                c[r] = (bf16_t)val;
            }
            *(bf16x4*)(Ps[wave] + l15 * 72 + j * 16 + quad * 4) = c;
        }
        bf16x8 t0 = *(const bf16x8*)(Ps[wave] + rr * 72 + cc);
        bf16x8 t1 = *(const bf16x8*)(Ps[wave] + rr * 72 + cc + 8);
        bf16_t* cp = ctx + (rowz + qb0 + u * 16 + rr) * DM + h * DH + cc;
        *(bf16x8*)cp = t0;
        *(bf16x8*)(cp + 8) = t1;
    }
}

extern "C" void kernel_launch(void* const* d_in, const int* in_sizes, int n_in,
                              void* d_out, int out_size, void* d_ws, size_t ws_size,
                              hipStream_t stream) {
    const float* Qe = (const float*)d_in[0];
    const float* Ke = (const float*)d_in[1];
    const float* Ve = (const float*)d_in[2];
    const int* Kini = (const int*)d_in[4];
    const float* WQ = (const float*)d_in[5];
    const float* WK = (const float*)d_in[6];
    const float* WV = (const float*)d_in[7];
    const float* WO = (const float*)d_in[8];
    float* out = (float*)d_out;

    const size_t EMB = (size_t)BATCH * S_LEN * DM;   // 8M elems
    const size_t SB  = (size_t)S_LEN * DM;           // 2M elems
    const size_t WSZ = (size_t)DM * DM;              // 1M elems
    const size_t need_full = (6 * EMB + 4 * WSZ) * sizeof(bf16_t)
                           + (size_t)BATCH * DM * sizeof(float);

    dim3 tb32(32, 8), tg32(32, 32);
    const float qscale = 0.125f * LOG2E;             // 1/sqrt(dh) * log2e

    if (ws_size >= need_full) {
        // ---- full-batch path (M = 8192) ----
        bf16_t* Qb  = (bf16_t*)d_ws;
        bf16_t* Kb  = Qb + EMB;
        bf16_t* Vb  = Kb + EMB;                 // becomes VT after V-GEMM
        bf16_t* WQt = Vb + EMB;
        bf16_t* WKt = WQt + WSZ;
        bf16_t* WVt = WKt + WSZ;
        bf16_t* WOt = WVt + WSZ;
        bf16_t* Qp  = WOt + WSZ;
        bf16_t* Kp  = Qp + EMB;
        bf16_t* Vp  = Kp + EMB;
        float*  Vm  = (float*)(Vp + EMB);
        bf16_t* Cx  = Qp;   // alias, block-disjoint (see attn_kernel)
        bf16_t* VT  = Vb;   // reuse spent Vb buffer

        int cg = (int)(EMB / (8 * 256));
        cvt3_bf16<<<dim3(cg, 3), 256, 0, stream>>>(Qe, Ke, Ve, Qb, Kb, Vb, (int)EMB);
        wtrans<<<tg32, tb32, 0, stream>>>(WQ, WQt, qscale);  // fold scale+log2e
        wtrans<<<tg32, tb32, 0, stream>>>(WK, WKt, 1.0f);
        wtrans<<<tg32, tb32, 0, stream>>>(WV, WVt, 1.0f);
        wtrans<<<tg32, tb32, 0, stream>>>(WO, WOt, 1.0f);

        // batched Q/K/V projection: one dispatch, blockIdx.z picks the triple
        gemm_nt_256<bf16_t><<<dim3(8192 / 256, DM / 128, 3), 512, 0, stream>>>(
            Qb, WQt, Qp, 8192, DM, DM, 1.0f, EMB, WSZ, EMB);

        btrans<<<dim3(DM / 32, 8192 / 32), tb32, 0, stream>>>(Vp, VT, 8192, DM);
        vmean_kernel<<<dim3(DM / 64, BATCH), 256, 0, stream>>>(Vp, Vm);
        attn_kernel<<<dim3((S_LEN / 128) * NH * BATCH), 256, 0, stream>>>(
            Qp, Kp, VT, Kini, Vm, Cx, 8192, S_LEN / 128);

        gemm_nt_256<float><<<dim3(8192 / 256, DM / 128, 1), 512, 0, stream>>>(
            Cx, WOt, out, 8192, DM, DM, 1.0f, 0, 0, 0);
    } else {
        // ---- per-batch fallback (M = 2048, ~34 MB workspace) ----
        bf16_t* Qb  = (bf16_t*)d_ws;
        bf16_t* Kb  = Qb + SB;
        bf16_t* Vb  = Kb + SB;
        bf16_t* WQt = Vb + SB;
        bf16_t* WKt = WQt + WSZ;
        bf16_t* WVt = WKt + WSZ;
        bf16_t* WOt = WVt + WSZ;
        bf16_t* Qp  = WOt + WSZ;
        bf16_t* Kp  = Qp + SB;
        bf16_t* Vp  = Kp + SB;
        float*  Vm  = (float*)(Vp + SB);
        bf16_t* Cx  = Qp;
        bf16_t* VT  = Vb;

        wtrans<<<tg32, tb32, 0, stream>>>(WQ, WQt, qscale);
        wtrans<<<tg32, tb32, 0, stream>>>(WK, WKt, 1.0f);
        wtrans<<<tg32, tb32, 0, stream>>>(WV, WVt, 1.0f);
        wtrans<<<tg32, tb32, 0, stream>>>(WO, WOt, 1.0f);

        int cg = (int)(SB / (8 * 256));
        for (int b = 0; b < BATCH; ++b) {
            const size_t off = (size_t)b * SB;
            cvt3_bf16<<<dim3(cg, 3), 256, 0, stream>>>(
                Qe + off, Ke + off, Ve + off, Qb, Kb, Vb, (int)SB);
            gemm_nt_256<bf16_t><<<dim3(2048 / 256, DM / 128, 3), 512, 0, stream>>>(
                Qb, WQt, Qp, 2048, DM, DM, 1.0f, SB, WSZ, SB);
            btrans<<<dim3(DM / 32, 2048 / 32), tb32, 0, stream>>>(Vp, VT, 2048, DM);
            vmean_kernel<<<dim3(DM / 64, 1), 256, 0, stream>>>(Vp, Vm);
            attn_kernel<<<dim3((S_LEN / 128) * NH), 256, 0, stream>>>(
                Qp, Kp, VT, Kini + (size_t)b * S_LEN, Vm, Cx, 2048, S_LEN / 128);
            gemm_nt_256<float><<<dim3(2048 / 256, DM / 128, 1), 512, 0, stream>>>(
                Cx, WOt, out + off, 2048, DM, DM, 1.0f, 0, 0, 0);
        }
    }
}

// Round 10
// 342.846 us; speedup vs baseline: 1.2313x; 1.2313x over previous
//
#include <hip/hip_runtime.h>

typedef __bf16 bf16_t;
typedef __bf16 bf16x8 __attribute__((ext_vector_type(8)));
typedef __bf16 bf16x4 __attribute__((ext_vector_type(4)));
typedef float  f32x4  __attribute__((ext_vector_type(4)));

#define S_LEN 2048
#define NH    16
#define DH    64
#define DM    1024
#define BATCH 4
#define LOG2E 1.44269504088896f
#define NEGB  (-1.44269504e10f)

static __device__ __forceinline__ f32x4 mfma16(bf16x8 a, bf16x8 b, f32x4 c) {
    return __builtin_amdgcn_mfma_f32_16x16x32_bf16(a, b, c, 0, 0, 0);
}

// bare v_exp_f32 (2^x): OCML exp2f adds range-handling VALU ops we don't need
// (|scores| are small); __expf would re-add the log2e multiply we folded away.
#if __has_builtin(__builtin_amdgcn_exp2f)
static __device__ __forceinline__ float exp2_hw(float x) {
    return __builtin_amdgcn_exp2f(x);
}
#else
static __device__ __forceinline__ float exp2_hw(float x) {
    float r;
    asm("v_exp_f32 %0, %1" : "=v"(r) : "v"(x));
    return r;
}
#endif

// async global->LDS, 16B per lane. lds base is wave-uniform; HW adds lane*16.
static __device__ __forceinline__ void gl_lds16(const bf16_t* g, bf16_t* l) {
    __builtin_amdgcn_global_load_lds(
        (const __attribute__((address_space(1))) unsigned int*)g,
        (__attribute__((address_space(3))) unsigned int*)l, 16, 0, 0);
}

// ---------------- fp32 -> bf16 convert, 3 tensors in one dispatch ------------
__global__ __launch_bounds__(256) void cvt3_bf16(const float* __restrict__ s0,
                                                 const float* __restrict__ s1,
                                                 const float* __restrict__ s2,
                                                 bf16_t* __restrict__ d0,
                                                 bf16_t* __restrict__ d1,
                                                 bf16_t* __restrict__ d2, int n) {
    int z = blockIdx.y;
    const float* s = (z == 0) ? s0 : (z == 1) ? s1 : s2;
    bf16_t*      d = (z == 0) ? d0 : (z == 1) ? d1 : d2;
    int i = (blockIdx.x * 256 + threadIdx.x) * 8;
    if (i >= n) return;
    const float4* q = (const float4*)(s + i);
    float4 a = q[0], b = q[1];
    bf16x8 r;
    r[0] = (bf16_t)a.x; r[1] = (bf16_t)a.y; r[2] = (bf16_t)a.z; r[3] = (bf16_t)a.w;
    r[4] = (bf16_t)b.x; r[5] = (bf16_t)b.y; r[6] = (bf16_t)b.z; r[7] = (bf16_t)b.w;
    *(bf16x8*)(d + i) = r;
}

// ---------------- weight transpose+convert: Wt[n][k] = scale * W[k][n] -------
__global__ __launch_bounds__(256) void wtrans(const float* __restrict__ W,
                                              bf16_t* __restrict__ Wt, float scale) {
    __shared__ bf16_t tile[32][33];
    int x = threadIdx.x, ty = threadIdx.y;
    int bx = blockIdx.x * 32, by = blockIdx.y * 32;
#pragma unroll
    for (int i = 0; i < 4; ++i) {
        int y = ty * 4 + i;
        tile[y][x] = (bf16_t)(W[(by + y) * DM + bx + x] * scale);
    }
    __syncthreads();
#pragma unroll
    for (int i = 0; i < 4; ++i) {
        int y = ty * 4 + i;
        Wt[(bx + y) * DM + by + x] = tile[x][y];
    }
}

// ---------------- NT GEMM, 256x128 tile, BK=64, z-batched --------------------
// m97 2-barrier structure, 512 threads / 8 waves (4x2 grid of 64x64 per-wave
// outputs), split-kk LDS layout, two K=32 sub-steps per barrier pair.
// blockIdx.z selects an (A, Bt, C) triple via strides (batched QKV projection).
// tz: z-index whose C is written TRANSPOSED (C^T[n][m], leading dim ldct) —
// fuses the V transpose into the projection (acc[i][j][r] is contiguous over r
// in C^T's m-dim -> one 8B bf16x4 store per (i,j), fully coalesced). tz=-1
// disables. Only valid for CT=bf16 launches (guarded at runtime).
template <typename CT>
__global__ __launch_bounds__(512) void gemm_nt_256(const bf16_t* __restrict__ A,
                                                   const bf16_t* __restrict__ Bt,
                                                   CT* __restrict__ C,
                                                   int M, int N, int K, float alpha,
                                                   size_t zsA, size_t zsB, size_t zsC,
                                                   int tz, int ldct) {
    __shared__ __align__(16) bf16_t As[2 * 256 * 32];  // [kk][row][32]
    __shared__ __align__(16) bf16_t Bs[2 * 128 * 32];
    A  += (size_t)blockIdx.z * zsA;
    Bt += (size_t)blockIdx.z * zsB;
    C  += (size_t)blockIdx.z * zsC;
    int tid = threadIdx.x, wave = tid >> 6, lane = tid & 63;
    int l15 = lane & 15, quad = lane >> 4;
    int wm = wave >> 1, wn = wave & 1;                 // 4 x 2 wave grid
    int bm = blockIdx.x * 256, bn = blockIdx.y * 128;
    int srow = lane >> 2, skx = (lane & 3) << 3;       // 16 rows x 4 chunks

    f32x4 acc[4][4] = {};

    for (int k0 = 0; k0 < K; k0 += 64) {
#pragma unroll
        for (int c = 0; c < 4; ++c) {
            int t = wave * 4 + c;
            int kk = t & 1, rb = (t >> 1) * 16;
            gl_lds16(A + (size_t)(bm + rb + srow) * K + k0 + kk * 32 + skx,
                     As + kk * 8192 + rb * 32);
        }
#pragma unroll
        for (int c = 0; c < 2; ++c) {
            int t = wave * 2 + c;
            int kk = t & 1, rb = (t >> 1) * 16;
            gl_lds16(Bt + (size_t)(bn + rb + srow) * K + k0 + kk * 32 + skx,
                     Bs + kk * 4096 + rb * 32);
        }
        __syncthreads();   // compiler drains vmcnt before s_barrier

#pragma unroll
        for (int kk = 0; kk < 2; ++kk) {
            bf16x8 af[4], bfr[4];
#pragma unroll
            for (int i = 0; i < 4; ++i)
                af[i] = *(const bf16x8*)(As + kk * 8192 +
                                         (wm * 64 + i * 16 + l15) * 32 + quad * 8);
#pragma unroll
            for (int j = 0; j < 4; ++j)
                bfr[j] = *(const bf16x8*)(Bs + kk * 4096 +
                                          (wn * 64 + j * 16 + l15) * 32 + quad * 8);
#pragma unroll
            for (int i = 0; i < 4; ++i)
#pragma unroll
                for (int j = 0; j < 4; ++j)
                    acc[i][j] = mfma16(af[i], bfr[j], acc[i][j]);
        }
        __syncthreads();
    }

    if ((int)blockIdx.z == tz) {                       // transposed C^T write
#pragma unroll
        for (int i = 0; i < 4; ++i)
#pragma unroll
            for (int j = 0; j < 4; ++j) {
                int n = bn + wn * 64 + j * 16 + l15;
                int m = bm + wm * 64 + i * 16 + quad * 4;
                bf16x4 c;
#pragma unroll
                for (int r = 0; r < 4; ++r) c[r] = (bf16_t)(acc[i][j][r] * alpha);
                *(bf16x4*)((bf16_t*)C + (size_t)n * ldct + m) = c;
            }
    } else {
#pragma unroll
        for (int i = 0; i < 4; ++i)
#pragma unroll
            for (int r = 0; r < 4; ++r) {
                int row = bm + wm * 64 + i * 16 + quad * 4 + r;
#pragma unroll
                for (int j = 0; j < 4; ++j)
                    C[(size_t)row * N + bn + wn * 64 + j * 16 + l15] =
                        (CT)(acc[i][j][r] * alpha);
            }
    }
}

// ---------------- V column mean from VT rows (fully-masked-row fallback) -----
// VT is [DM][ldv]; batch z occupies columns [z*S_LEN, z*S_LEN+S_LEN).
// Row-major contiguous bf16x8 loads (vs the old 2048-stride scalar reads).
__global__ __launch_bounds__(256) void vmean_vt(const bf16_t* __restrict__ VT,
                                                float* __restrict__ Vm, int ldv) {
    __shared__ float red[64][4];
    int z = blockIdx.y;
    int row = blockIdx.x * 64 + (threadIdx.x >> 2);
    int part = threadIdx.x & 3;
    const bf16_t* p = VT + (size_t)row * ldv + (size_t)z * S_LEN + part * 512;
    float s = 0.f;
    for (int i = 0; i < 64; ++i) {
        bf16x8 v = *(const bf16x8*)(p + i * 8);
#pragma unroll
        for (int j = 0; j < 8; ++j) s += (float)v[j];
    }
    red[threadIdx.x >> 2][part] = s;
    __syncthreads();
    if (threadIdx.x < 64) {
        float t = red[threadIdx.x][0] + red[threadIdx.x][1] +
                  red[threadIdx.x][2] + red[threadIdx.x][3];
        Vm[z * DM + blockIdx.x * 64 + threadIdx.x] = t * (1.0f / S_LEN);
    }
}

// ---------------- fused attention: swapped QK^T / PV, NO-MAX softmax ---------
// (Reverted to the round-5 kernel: best measured variant, 86.9 us, clean
// counters. Round-9's barrier-free global-fragment variant regressed 1.8x —
// L2/L3 latency on the MFMA operand path can't be hidden at this occupancy;
// LDS staging is load-bearing as a LATENCY amortizer.)
// S^T = mfma(K,Q), ctx^T = mfma(V^T,P^T): each lane owns a full 16-score slice
// of ONE query row. Scores arrive pre-scaled by log2e (folded into WQ).
// No-max softmax: scores structurally bounded -> p = 2^s directly (no
// overflow; masked -> exactly 0); l kept as per-lane f32x4 partial, reduced
// once in the epilogue; dead rows detected by l == 0 (Vmean fallback).
// Causal compare only on the diagonal tile.
// ctx may alias Qp: block reads only its own (rows x head) slice at start and
// writes only that same slice at the end; slices are disjoint across blocks.
__global__ __launch_bounds__(256) void attn_kernel(const bf16_t* __restrict__ Qp,
                                                   const bf16_t* __restrict__ Kp,
                                                   const bf16_t* __restrict__ VT,
                                                   const int* __restrict__ Kini,
                                                   const float* __restrict__ Vmean,
                                                   bf16_t* __restrict__ ctx,
                                                   int ldv, int nqt) {
    __shared__ __align__(16) bf16_t Ks[64 * 72];     // [key][dh], stride 72
    __shared__ __align__(16) bf16_t VsT[64 * 72];    // [dh][key], stride 72
    __shared__ __align__(16) bf16_t Ps[4][16 * 72];  // per-wave P [qrow][key]
    __shared__ bf16_t padb[2048];                    // pad bias 0 / -1.44e10

    int bid = blockIdx.x;
    int qt = nqt - 1 - (bid >> 6);                   // heavy tiles first
    int hz = bid & 63;
    int h = hz & 15, z = hz >> 4;
    int tid = threadIdx.x, wave = tid >> 6, lane = tid & 63;
    int l15 = lane & 15, quad = lane >> 4;
    int qbase = qt * 64 + wave * 16;
    size_t rowz = (size_t)z * S_LEN;
    int ntiles = qt + 1;                             // causal: only kb <= q_max
    int nkeys = ntiles * 64;

    // pad-bias table, once per block (covered by first in-loop __syncthreads)
    for (int i = tid; i < nkeys; i += 256)
        padb[i] = (Kini[rowz + i] == 0) ? (bf16_t)NEGB : (bf16_t)(0.0f);

    const bf16_t* qptr = Qp + (rowz + qbase + l15) * DM + h * DH + quad * 8;
    bf16x8 qa0 = *(const bf16x8*)qptr;
    bf16x8 qa1 = *(const bf16x8*)(qptr + 32);

    f32x4 o[4] = {};                                 // ctx^T frags: col=q(l15)
    f32x4 l4 = {0.f, 0.f, 0.f, 0.f};                 // per-lane partial row-sum
    int q = qbase + l15;

    // staging assignment: 256 threads cover 64 rows x 64 elems, 2 b128 each
    int srow = tid >> 2, sch = (tid & 3) << 4;       // row 0..63, chunk 0/16/32/48
    const bf16_t* kgb = Kp + (rowz + srow) * DM + h * DH + sch;      // + kb*DM
    const bf16_t* vgb = VT + (size_t)(h * DH + srow) * ldv + rowz + sch;  // + kb

    // prefetch tile 0
    bf16x8 kr0 = *(const bf16x8*)kgb,        kr1 = *(const bf16x8*)(kgb + 8);
    bf16x8 vr0 = *(const bf16x8*)vgb,        vr1 = *(const bf16x8*)(vgb + 8);

    for (int kt = 0; kt < ntiles; ++kt) {
        int kb = kt * 64;
        // stage prefetched tile into LDS (pure b128 both tensors)
        *(bf16x8*)(Ks  + srow * 72 + sch)     = kr0;
        *(bf16x8*)(Ks  + srow * 72 + sch + 8) = kr1;
        *(bf16x8*)(VsT + srow * 72 + sch)     = vr0;
        *(bf16x8*)(VsT + srow * 72 + sch + 8) = vr1;
        __syncthreads();

        // issue next tile's global loads (clamped at last iter; wave-uniform)
        int nkb = (kt + 1 < ntiles) ? kb + 64 : kb;
        const bf16_t* kg = kgb + (size_t)nkb * DM;
        const bf16_t* vg = vgb + nkb;
        kr0 = *(const bf16x8*)kg; kr1 = *(const bf16x8*)(kg + 8);
        vr0 = *(const bf16x8*)vg; vr1 = *(const bf16x8*)(vg + 8);

        // S^T = mfma(K, Q): lane holds keys ks*16+quad*4+r for query q=l15
        f32x4 sv[4];
#pragma unroll
        for (int ks = 0; ks < 4; ++ks) {
            bf16x8 kf0 = *(const bf16x8*)(Ks + (ks * 16 + l15) * 72 + quad * 8);
            bf16x8 kf1 = *(const bf16x8*)(Ks + (ks * 16 + l15) * 72 + 32 + quad * 8);
            f32x4 s = {0.f, 0.f, 0.f, 0.f};
            s = mfma16(kf0, qa0, s);
            s = mfma16(kf1, qa1, s);
            bf16x4 pb = *(const bf16x4*)(padb + kb + ks * 16 + quad * 4);  // bcast
#pragma unroll
            for (int r = 0; r < 4; ++r) s[r] += (float)pb[r];
            sv[ks] = s;
        }
        if (kt == ntiles - 1) {                      // diagonal tile only
#pragma unroll
            for (int ks = 0; ks < 4; ++ks)
#pragma unroll
                for (int r = 0; r < 4; ++r)
                    if (kb + ks * 16 + quad * 4 + r > q) sv[ks][r] = NEGB;
        }

        // p = 2^s directly (no max subtraction; masked -> exactly 0)
#pragma unroll
        for (int ks = 0; ks < 4; ++ks) {
            f32x4 s = sv[ks];
#pragma unroll
            for (int r = 0; r < 4; ++r) s[r] = exp2_hw(s[r]);
            sv[ks] = s;
        }
        l4 += (sv[0] + sv[1]) + (sv[2] + sv[3]);     // defer reduce to epilogue
#pragma unroll
        for (int ks = 0; ks < 4; ++ks) {
            bf16x4 pk;
#pragma unroll
            for (int r = 0; r < 4; ++r) pk[r] = (bf16_t)sv[ks][r];
            *(bf16x4*)(Ps[wave] + l15 * 72 + ks * 16 + quad * 4) = pk;
        }

        // P reload as B-frag (same-wave ds ordering, compiler inserts lgkmcnt)
        bf16x8 pa0 = *(const bf16x8*)(Ps[wave] + l15 * 72 + quad * 8);
        bf16x8 pa1 = *(const bf16x8*)(Ps[wave] + l15 * 72 + 32 + quad * 8);
#pragma unroll
        for (int j = 0; j < 4; ++j) {
            bf16x8 vb0 = *(const bf16x8*)(VsT + (j * 16 + l15) * 72 + quad * 8);
            bf16x8 vb1 = *(const bf16x8*)(VsT + (j * 16 + l15) * 72 + 32 + quad * 8);
            o[j] = mfma16(vb0, pa0, o[j]);           // ctx^T = V^T . P^T
            o[j] = mfma16(vb1, pa1, o[j]);
        }
        __syncthreads();
    }

    // final l: horizontal over this lane's 4 partials + 2 cross-quad shuffles
    float l_ = (l4[0] + l4[1]) + (l4[2] + l4[3]);
    l_ += __shfl_xor(l_, 16);
    l_ += __shfl_xor(l_, 32);

    // epilogue: scale by 1/l, transpose ctx^T -> ctx through per-wave Ps,
    // 16B coalesced global stores. Fully-masked rows (l==0) -> Vmean.
    float inv = 1.0f / l_;
    bool dead = (l_ == 0.0f);
    if (__any(dead)) {
        const float* vm = Vmean + z * DM + h * DH;
#pragma unroll
        for (int j = 0; j < 4; ++j) {
            bf16x4 c;
#pragma unroll
            for (int r = 0; r < 4; ++r) {
                int dh = j * 16 + quad * 4 + r;
                float val = dead ? vm[dh] : o[j][r] * inv;
                c[r] = (bf16_t)val;
            }
            *(bf16x4*)(Ps[wave] + l15 * 72 + j * 16 + quad * 4) = c;
        }
    } else {
#pragma unroll
        for (int j = 0; j < 4; ++j) {
            bf16x4 c;
#pragma unroll
            for (int r = 0; r < 4; ++r) c[r] = (bf16_t)(o[j][r] * inv);
            *(bf16x4*)(Ps[wave] + l15 * 72 + j * 16 + quad * 4) = c;
        }
    }
    // same-wave cross-lane LDS read-back (lgkmcnt ordering, no barrier needed).
    // 64 lanes x 16 elems = full 16x64 tile: rr = q-row, cc = 16-elem chunk.
    int rr = lane >> 2, cc = (lane & 3) * 16;
    bf16x8 t0 = *(const bf16x8*)(Ps[wave] + rr * 72 + cc);
    bf16x8 t1 = *(const bf16x8*)(Ps[wave] + rr * 72 + cc + 8);
    bf16_t* cp = ctx + (rowz + qbase + rr) * DM + h * DH + cc;
    *(bf16x8*)cp = t0;
    *(bf16x8*)(cp + 8) = t1;
}

extern "C" void kernel_launch(void* const* d_in, const int* in_sizes, int n_in,
                              void* d_out, int out_size, void* d_ws, size_t ws_size,
                              hipStream_t stream) {
    const float* Qe = (const float*)d_in[0];
    const float* Ke = (const float*)d_in[1];
    const float* Ve = (const float*)d_in[2];
    const int* Kini = (const int*)d_in[4];
    const float* WQ = (const float*)d_in[5];
    const float* WK = (const float*)d_in[6];
    const float* WV = (const float*)d_in[7];
    const float* WO = (const float*)d_in[8];
    float* out = (float*)d_out;

    const size_t EMB = (size_t)BATCH * S_LEN * DM;   // 8M elems
    const size_t SB  = (size_t)S_LEN * DM;           // 2M elems
    const size_t WSZ = (size_t)DM * DM;              // 1M elems
    const size_t need_full = (6 * EMB + 4 * WSZ) * sizeof(bf16_t)
                           + (size_t)BATCH * DM * sizeof(float);

    dim3 tb32(32, 8), tg32(32, 32);
    const float qscale = 0.125f * LOG2E;             // 1/sqrt(dh) * log2e

    if (ws_size >= need_full) {
        // ---- full-batch path (M = 8192) ----
        bf16_t* Qb  = (bf16_t*)d_ws;
        bf16_t* Kb  = Qb + EMB;
        bf16_t* Vb  = Kb + EMB;
        bf16_t* WQt = Vb + EMB;
        bf16_t* WKt = WQt + WSZ;
        bf16_t* WVt = WKt + WSZ;
        bf16_t* WOt = WVt + WSZ;
        bf16_t* Qp  = WOt + WSZ;
        bf16_t* Kp  = Qp + EMB;
        bf16_t* VT  = Kp + EMB;   // V projection written TRANSPOSED [DM][8192]
        float*  Vm  = (float*)(VT + EMB);
        bf16_t* Cx  = Qp;   // alias, block-disjoint (see attn_kernel)

        int cg = (int)(EMB / (8 * 256));
        cvt3_bf16<<<dim3(cg, 3), 256, 0, stream>>>(Qe, Ke, Ve, Qb, Kb, Vb, (int)EMB);
        wtrans<<<tg32, tb32, 0, stream>>>(WQ, WQt, qscale);  // fold scale+log2e
        wtrans<<<tg32, tb32, 0, stream>>>(WK, WKt, 1.0f);
        wtrans<<<tg32, tb32, 0, stream>>>(WV, WVt, 1.0f);
        wtrans<<<tg32, tb32, 0, stream>>>(WO, WOt, 1.0f);

        // batched Q/K/V projection; z=2 (V) writes C^T directly (fused btrans)
        gemm_nt_256<bf16_t><<<dim3(8192 / 256, DM / 128, 3), 512, 0, stream>>>(
            Qb, WQt, Qp, 8192, DM, DM, 1.0f, EMB, WSZ, EMB, 2, 8192);

        vmean_vt<<<dim3(DM / 64, BATCH), 256, 0, stream>>>(VT, Vm, 8192);
        attn_kernel<<<dim3((S_LEN / 64) * NH * BATCH), 256, 0, stream>>>(
            Qp, Kp, VT, Kini, Vm, Cx, 8192, S_LEN / 64);

        gemm_nt_256<float><<<dim3(8192 / 256, DM / 128, 1), 512, 0, stream>>>(
            Cx, WOt, out, 8192, DM, DM, 1.0f, 0, 0, 0, -1, 0);
    } else {
        // ---- per-batch fallback (M = 2048, ~34 MB workspace) ----
        bf16_t* Qb  = (bf16_t*)d_ws;
        bf16_t* Kb  = Qb + SB;
        bf16_t* Vb  = Kb + SB;
        bf16_t* WQt = Vb + SB;
        bf16_t* WKt = WQt + WSZ;
        bf16_t* WVt = WKt + WSZ;
        bf16_t* WOt = WVt + WSZ;
        bf16_t* Qp  = WOt + WSZ;
        bf16_t* Kp  = Qp + SB;
        bf16_t* VT  = Kp + SB;    // V projection transposed [DM][2048]
        float*  Vm  = (float*)(VT + SB);
        bf16_t* Cx  = Qp;

        wtrans<<<tg32, tb32, 0, stream>>>(WQ, WQt, qscale);
        wtrans<<<tg32, tb32, 0, stream>>>(WK, WKt, 1.0f);
        wtrans<<<tg32, tb32, 0, stream>>>(WV, WVt, 1.0f);
        wtrans<<<tg32, tb32, 0, stream>>>(WO, WOt, 1.0f);

        int cg = (int)(SB / (8 * 256));
        for (int b = 0; b < BATCH; ++b) {
            const size_t off = (size_t)b * SB;
            cvt3_bf16<<<dim3(cg, 3), 256, 0, stream>>>(
                Qe + off, Ke + off, Ve + off, Qb, Kb, Vb, (int)SB);
            gemm_nt_256<bf16_t><<<dim3(2048 / 256, DM / 128, 3), 512, 0, stream>>>(
                Qb, WQt, Qp, 2048, DM, DM, 1.0f, SB, WSZ, SB, 2, 2048);
            vmean_vt<<<dim3(DM / 64, 1), 256, 0, stream>>>(VT, Vm, 2048);
            attn_kernel<<<dim3((S_LEN / 64) * NH), 256, 0, stream>>>(
                Qp, Kp, VT, Kini + (size_t)b * S_LEN, Vm, Cx, 2048, S_LEN / 64);
            gemm_nt_256<float><<<dim3(2048 / 256, DM / 128, 1), 512, 0, stream>>>(
                Cx, WOt, out + off, 2048, DM, DM, 1.0f, 0, 0, 0, -1, 0);
        }
    }
}